// Round 1
// baseline (560.129 us; speedup 1.0000x reference)
//
#include <hip/hip_runtime.h>
#include <math.h>

#define B_   16
#define C1_  128
#define C2_  128
#define H_   64
#define W_   64
#define HW_  4096   // H_*W_
#define NCH_ 27     // 18 offset + 9 mask channels

// ---------------------------------------------------------------------------
// Kernel 0: transpose w_conv[oc][c][n] -> wt[n][c][oc] (coalesced writes)
// ---------------------------------------------------------------------------
__global__ __launch_bounds__(256) void wtrans_k(const float* __restrict__ wc,
                                                float* __restrict__ wt) {
  int idx = blockIdx.x * 256 + threadIdx.x;   // enumerate wt linearly
  if (idx >= 9 * 128 * 128) return;
  int oc = idx & 127;
  int c  = (idx >> 7) & 127;
  int n  = idx >> 14;
  wt[idx] = wc[(oc * 128 + c) * 9 + n];
}

// ---------------------------------------------------------------------------
// Kernel 1: offset (ch 0..17) + mask (ch 18..26, sigmoid) 3x3 conv, pad 1.
// Block = one (b,h) row, 256 threads = 64 px * 4 wave-uniform channel groups
// of 7 channels each (28 slots cover 27 channels).
// om layout: [B][27][H][W]
// ---------------------------------------------------------------------------
__global__ __launch_bounds__(256) void offmask_k(
    const float* __restrict__ x,
    const float* __restrict__ w_off, const float* __restrict__ b_off,
    const float* __restrict__ w_mask, const float* __restrict__ b_mask,
    float* __restrict__ om) {
  int bh = blockIdx.x;              // 0..1023
  int b = bh >> 6, h = bh & 63;
  int t = threadIdx.x;
  int px = t & 63;
  int grp = __builtin_amdgcn_readfirstlane(t >> 6);   // wave-uniform -> s_loads

  float acc[7];
#pragma unroll
  for (int i = 0; i < 7; ++i) acc[i] = 0.f;

  const float* xb = x + (size_t)b * C1_ * HW_;
  for (int c = 0; c < C1_; ++c) {
    const float* xc = xb + c * HW_;
    float xv[9];
#pragma unroll
    for (int r = 0; r < 3; ++r) {
      int hh = h - 1 + r;
#pragma unroll
      for (int d = 0; d < 3; ++d) {
        int ww = px - 1 + d;
        bool ok = ((unsigned)hh < 64u) && ((unsigned)ww < 64u);
        xv[r * 3 + d] = ok ? xc[hh * 64 + ww] : 0.f;
      }
    }
#pragma unroll
    for (int i = 0; i < 7; ++i) {
      int ch = grp * 7 + i;
      if (ch < NCH_) {
        const float* wp = (ch < 18) ? (w_off + (ch * 128 + c) * 9)
                                    : (w_mask + ((ch - 18) * 128 + c) * 9);
        float s = acc[i];
#pragma unroll
        for (int k = 0; k < 9; ++k) s = fmaf(xv[k], wp[k], s);
        acc[i] = s;
      }
    }
  }

  float* omb = om + (size_t)b * NCH_ * HW_ + h * 64 + px;
#pragma unroll
  for (int i = 0; i < 7; ++i) {
    int ch = grp * 7 + i;
    if (ch < NCH_) {
      float v = acc[i] + ((ch < 18) ? b_off[ch] : b_mask[ch - 18]);
      if (ch >= 18) v = 1.f / (1.f + __expf(-v));   // sigmoid for mask
      omb[(size_t)ch * HW_] = v;
    }
  }
}

// ---------------------------------------------------------------------------
// Kernel 2: deformable sampling + implicit GEMM.
// Block = one (b,h) row: 128 oc x 64 px outputs.
// Per tap n: sample samp[128c][64px] into LDS, then 8oc x 4px register-tiled
// f32 GEMM, weights staged per 64-c half into LDS (coalesced from wt).
// ---------------------------------------------------------------------------
__global__ __launch_bounds__(256) void dcn_k(const float* __restrict__ x,
                                             const float* __restrict__ wt,
                                             const float* __restrict__ om,
                                             float* __restrict__ out) {
  __shared__ float samp[128][64];   // 32 KB  samp[c][px]
  __shared__ float wlds[64][128];   // 32 KB  wlds[k][oc]

  int bh = blockIdx.x;
  int b = bh >> 6, h = bh & 63;
  int t = threadIdx.x;
  int q = t & 15;     // px quad: px = q*4 + p
  int g = t >> 4;     // oc group: oc = g*8 + j

  float acc[8][4];
#pragma unroll
  for (int j = 0; j < 8; ++j)
#pragma unroll
    for (int p = 0; p < 4; ++p) acc[j][p] = 0.f;

  const float* xb = x + (size_t)b * C1_ * HW_;
  const float* omp_ = om + (size_t)b * NCH_ * HW_ + h * 64;

  int spx = t & 63;            // sampling: this thread's pixel
  int c0  = (t >> 6) * 32;     // sampling: this thread's channel range

  for (int n = 0; n < 9; ++n) {
    __syncthreads();   // protect samp (read last iter) before overwrite

    // ---- bilinear sampling into samp[c][spx], coords computed once ----
    {
      float oy = omp_[(2 * n) * HW_ + spx];
      float ox = omp_[(2 * n + 1) * HW_ + spx];
      float m  = omp_[(18 + n) * HW_ + spx];
      float py  = oy + (float)(h - 1 + n / 3);
      float pxf = ox + (float)(spx - 1 + n % 3);
      float y0f = floorf(py), x0f = floorf(pxf);
      int y0 = (int)y0f, x0 = (int)x0f;
      float wy1 = py - y0f, wx1 = pxf - x0f;
      float wy0 = 1.f - wy1, wx0 = 1.f - wx1;
      bool vy0 = (unsigned)y0 < 64u, vy1 = (unsigned)(y0 + 1) < 64u;
      bool vx0 = (unsigned)x0 < 64u, vx1 = (unsigned)(x0 + 1) < 64u;
      int y0c = min(max(y0, 0), 63), y1c = min(max(y0 + 1, 0), 63);
      int x0c = min(max(x0, 0), 63), x1c = min(max(x0 + 1, 0), 63);
      float w00 = (vy0 && vx0) ? wy0 * wx0 * m : 0.f;
      float w01 = (vy0 && vx1) ? wy0 * wx1 * m : 0.f;
      float w10 = (vy1 && vx0) ? wy1 * wx0 * m : 0.f;
      float w11 = (vy1 && vx1) ? wy1 * wx1 * m : 0.f;
      int i00 = y0c * 64 + x0c, i01 = y0c * 64 + x1c;
      int i10 = y1c * 64 + x0c, i11 = y1c * 64 + x1c;
      const float* xc = xb + (size_t)c0 * HW_;
#pragma unroll 4
      for (int j = 0; j < 32; ++j) {
        float v = w00 * xc[i00] + w01 * xc[i01] + w10 * xc[i10] + w11 * xc[i11];
        samp[c0 + j][spx] = v;
        xc += HW_;
      }
    }

    // ---- GEMM over the 128-c dim in two 64-c halves ----
#pragma unroll
    for (int half = 0; half < 2; ++half) {
      __syncthreads();   // half0: sampling done; also wlds safe to overwrite
      const float* wsrc = wt + ((size_t)n * 128 + half * 64) * 128;
      for (int idx = t; idx < 64 * 128; idx += 256)
        wlds[idx >> 7][idx & 127] = wsrc[idx];
      __syncthreads();

      int cbase = half * 64;
#pragma unroll 2
      for (int k = 0; k < 64; ++k) {
        const float4 s  = *reinterpret_cast<const float4*>(&samp[cbase + k][q * 4]);
        const float4 w0 = *reinterpret_cast<const float4*>(&wlds[k][g * 8]);
        const float4 w1 = *reinterpret_cast<const float4*>(&wlds[k][g * 8 + 4]);
        const float* sv  = &s.x;
        const float* wv0 = &w0.x;
        const float* wv1 = &w1.x;
#pragma unroll
        for (int j = 0; j < 4; ++j)
#pragma unroll
          for (int p = 0; p < 4; ++p) {
            acc[j][p]     = fmaf(wv0[j], sv[p], acc[j][p]);
            acc[j + 4][p] = fmaf(wv1[j], sv[p], acc[j + 4][p]);
          }
      }
    }
  }

  // ---- write out[b][oc][h][px] ----
  float* ob = out + ((size_t)b * C2_ + g * 8) * HW_ + h * 64 + q * 4;
#pragma unroll
  for (int j = 0; j < 8; ++j) {
    float4 o;
    o.x = acc[j][0]; o.y = acc[j][1]; o.z = acc[j][2]; o.w = acc[j][3];
    *reinterpret_cast<float4*>(ob + (size_t)j * HW_) = o;
  }
}

// ---------------------------------------------------------------------------
extern "C" void kernel_launch(void* const* d_in, const int* in_sizes, int n_in,
                              void* d_out, int out_size, void* d_ws, size_t ws_size,
                              hipStream_t stream) {
  const float* x      = (const float*)d_in[0];
  const float* w_conv = (const float*)d_in[1];
  const float* w_off  = (const float*)d_in[2];
  const float* b_off  = (const float*)d_in[3];
  const float* w_mask = (const float*)d_in[4];
  const float* b_mask = (const float*)d_in[5];
  float* out = (float*)d_out;

  // workspace layout: om [16*27*4096] floats, then wt [9*128*128] floats
  float* om = (float*)d_ws;
  float* wt = om + (size_t)B_ * NCH_ * HW_;

  hipLaunchKernelGGL(wtrans_k, dim3((9 * 128 * 128 + 255) / 256), dim3(256), 0,
                     stream, w_conv, wt);
  hipLaunchKernelGGL(offmask_k, dim3(B_ * H_), dim3(256), 0, stream,
                     x, w_off, b_off, w_mask, b_mask, om);
  hipLaunchKernelGGL(dcn_k, dim3(B_ * H_), dim3(256), 0, stream,
                     x, wt, om, out);
}

// Round 2
// 380.039 us; speedup vs baseline: 1.4739x; 1.4739x over previous
//
#include <hip/hip_runtime.h>
#include <math.h>

#define B_   16
#define C1_  128
#define C2_  128
#define H_   64
#define W_   64
#define HW_  4096
#define NCH_ 27

typedef __attribute__((ext_vector_type(8))) short  bf16x8;   // 8 bf16 (4 VGPRs)
typedef __attribute__((ext_vector_type(8))) unsigned short u16x8;
typedef __attribute__((ext_vector_type(4))) float  f32x4;

__device__ __forceinline__ unsigned short f2bf(float f) {
  unsigned int u = __builtin_bit_cast(unsigned int, f);
  u += 0x7fff + ((u >> 16) & 1);          // round-to-nearest-even
  return (unsigned short)(u >> 16);
}

// ---------------------------------------------------------------------------
// Kernel 0: pack w_conv[oc][c][n] into bf16 B-fragments for 16x16x32 MFMA.
// wpk[n][ot][kb][lane][j] = w_conv[oc = ot*16 + (lane&15)][c = kb*32 + (lane>>4)*8 + j][n]
// so a lane's 8 k-elements are 16 contiguous bytes -> one dwordx4 per fragment.
// ---------------------------------------------------------------------------
__global__ __launch_bounds__(256) void wpack_k(const float* __restrict__ wc,
                                               unsigned short* __restrict__ wpk) {
  int idx = blockIdx.x * 256 + threadIdx.x;
  if (idx >= 9 * 8 * 4 * 64 * 8) return;
  int j  = idx & 7;
  int l  = (idx >> 3) & 63;
  int kb = (idx >> 9) & 3;
  int ot = (idx >> 11) & 7;
  int n  = idx >> 14;
  int oc = ot * 16 + (l & 15);
  int c  = kb * 32 + (l >> 4) * 8 + j;
  wpk[idx] = f2bf(wc[(oc * 128 + c) * 9 + n]);
}

// ---------------------------------------------------------------------------
// Kernel 1: offset (ch 0..17) + mask (ch 18..26, sigmoid) 3x3 conv, pad 1.
// Unchanged from round 1 except XCD-chunked block swizzle.
// ---------------------------------------------------------------------------
__global__ __launch_bounds__(256) void offmask_k(
    const float* __restrict__ x,
    const float* __restrict__ w_off, const float* __restrict__ b_off,
    const float* __restrict__ w_mask, const float* __restrict__ b_mask,
    float* __restrict__ om) {
  int bid = blockIdx.x;
  int bh = ((bid & 7) << 7) | (bid >> 3);   // XCD-chunked (1024 % 8 == 0)
  int b = bh >> 6, h = bh & 63;
  int t = threadIdx.x;
  int px = t & 63;
  int grp = __builtin_amdgcn_readfirstlane(t >> 6);

  float acc[7];
#pragma unroll
  for (int i = 0; i < 7; ++i) acc[i] = 0.f;

  const float* xb = x + (size_t)b * C1_ * HW_;
  for (int c = 0; c < C1_; ++c) {
    const float* xc = xb + c * HW_;
    float xv[9];
#pragma unroll
    for (int r = 0; r < 3; ++r) {
      int hh = h - 1 + r;
#pragma unroll
      for (int d = 0; d < 3; ++d) {
        int ww = px - 1 + d;
        bool ok = ((unsigned)hh < 64u) && ((unsigned)ww < 64u);
        xv[r * 3 + d] = ok ? xc[hh * 64 + ww] : 0.f;
      }
    }
#pragma unroll
    for (int i = 0; i < 7; ++i) {
      int ch = grp * 7 + i;
      if (ch < NCH_) {
        const float* wp = (ch < 18) ? (w_off + (ch * 128 + c) * 9)
                                    : (w_mask + ((ch - 18) * 128 + c) * 9);
        float s = acc[i];
#pragma unroll
        for (int k = 0; k < 9; ++k) s = fmaf(xv[k], wp[k], s);
        acc[i] = s;
      }
    }
  }

  float* omb = om + (size_t)b * NCH_ * HW_ + h * 64 + px;
#pragma unroll
  for (int i = 0; i < 7; ++i) {
    int ch = grp * 7 + i;
    if (ch < NCH_) {
      float v = acc[i] + ((ch < 18) ? b_off[ch] : b_mask[ch - 18]);
      if (ch >= 18) v = 1.f / (1.f + __expf(-v));
      omb[(size_t)ch * HW_] = v;
    }
  }
}

// ---------------------------------------------------------------------------
// Kernel 2: deformable sampling (bf16 into swizzled LDS) + MFMA implicit GEMM.
// Block = one (b,h) row: 128 oc x 64 px. 4 waves, wave w owns oc [w*32,w*32+32).
// samp LDS layout: element (px, c) at byte (px*256 + c*2) ^ ((px&7)<<4).
// ---------------------------------------------------------------------------
__global__ __launch_bounds__(256) void dcn_k(const float* __restrict__ x,
                                             const unsigned short* __restrict__ wpk,
                                             const float* __restrict__ om,
                                             float* __restrict__ out) {
  __shared__ unsigned short samp[64 * 128];   // 16 KB bf16, swizzled

  int bid = blockIdx.x;
  int bh = ((bid & 7) << 7) | (bid >> 3);     // XCD-chunked swizzle
  int b = bh >> 6, h = bh & 63;
  int t = threadIdx.x;
  int l = t & 63;
  int w = t >> 6;          // wave id -> oc base w*32
  int spx = t & 63;        // sampling pixel
  int c0  = (t >> 6) * 32; // sampling channel range

  f32x4 acc[4][2];
#pragma unroll
  for (int m = 0; m < 4; ++m)
#pragma unroll
    for (int t2 = 0; t2 < 2; ++t2) acc[m][t2] = (f32x4)0.f;

  const float* xb = x + (size_t)b * C1_ * HW_;
  const float* omp_ = om + (size_t)b * NCH_ * HW_ + h * 64;

  for (int n = 0; n < 9; ++n) {
    __syncthreads();   // samp consumed by previous tap's MFMA

    // ---- bilinear sampling into swizzled bf16 samp ----
    {
      float oy = omp_[(2 * n) * HW_ + spx];
      float ox = omp_[(2 * n + 1) * HW_ + spx];
      float m_ = omp_[(18 + n) * HW_ + spx];
      float py  = oy + (float)(h - 1 + n / 3);
      float pxf = ox + (float)(spx - 1 + n % 3);
      float y0f = floorf(py), x0f = floorf(pxf);
      int y0 = (int)y0f, x0 = (int)x0f;
      float wy1 = py - y0f, wx1 = pxf - x0f;
      float wy0 = 1.f - wy1, wx0 = 1.f - wx1;
      bool vy0 = (unsigned)y0 < 64u, vy1 = (unsigned)(y0 + 1) < 64u;
      bool vx0 = (unsigned)x0 < 64u, vx1 = (unsigned)(x0 + 1) < 64u;
      int y0c = min(max(y0, 0), 63), y1c = min(max(y0 + 1, 0), 63);
      int x0c = min(max(x0, 0), 63), x1c = min(max(x0 + 1, 0), 63);
      float w00 = (vy0 && vx0) ? wy0 * wx0 * m_ : 0.f;
      float w01 = (vy0 && vx1) ? wy0 * wx1 * m_ : 0.f;
      float w10 = (vy1 && vx0) ? wy1 * wx0 * m_ : 0.f;
      float w11 = (vy1 && vx1) ? wy1 * wx1 * m_ : 0.f;
      int i00 = y0c * 64 + x0c, i01 = y0c * 64 + x1c;
      int i10 = y1c * 64 + x0c, i11 = y1c * 64 + x1c;
      const float* xc = xb + (size_t)c0 * HW_;
#pragma unroll 1
      for (int i = 0; i < 4; ++i) {
        u16x8 pk;
#pragma unroll
        for (int jj = 0; jj < 8; ++jj) {
          float v = w00 * xc[i00] + w01 * xc[i01] + w10 * xc[i10] + w11 * xc[i11];
          pk[jj] = f2bf(v);
          xc += HW_;
        }
        unsigned off = (unsigned)(spx * 256 + (c0 + i * 8) * 2);
        off ^= (spx & 7) << 4;
        *reinterpret_cast<u16x8*>(reinterpret_cast<char*>(samp) + off) = pk;
      }
    }

    __syncthreads();

    // ---- MFMA over K=128 channels in 4 k-blocks of 32 ----
    const unsigned short* wp = wpk + (((size_t)n * 8 + w * 2) * 4) * 64 * 8;
#pragma unroll
    for (int kb = 0; kb < 4; ++kb) {
      bf16x8 bfr0 = *reinterpret_cast<const bf16x8*>(wp + ((size_t)(0 * 4 + kb) * 64 + l) * 8);
      bf16x8 bfr1 = *reinterpret_cast<const bf16x8*>(wp + ((size_t)(1 * 4 + kb) * 64 + l) * 8);
      int kbyte = kb * 64 + (l >> 4) * 16;
#pragma unroll
      for (int m = 0; m < 4; ++m) {
        int px = m * 16 + (l & 15);
        unsigned off = (unsigned)(px * 256 + kbyte) ^ ((px & 7) << 4);
        bf16x8 afr = *reinterpret_cast<const bf16x8*>(
            reinterpret_cast<const char*>(samp) + off);
        acc[m][0] = __builtin_amdgcn_mfma_f32_16x16x32_bf16(afr, bfr0, acc[m][0], 0, 0, 0);
        acc[m][1] = __builtin_amdgcn_mfma_f32_16x16x32_bf16(afr, bfr1, acc[m][1], 0, 0, 0);
      }
    }
  }

  // ---- write out: D row=(lane>>4)*4+reg (px), col=lane&15 (oc) ----
  int px0 = (l >> 4) * 4;
#pragma unroll
  for (int m = 0; m < 4; ++m)
#pragma unroll
    for (int t2 = 0; t2 < 2; ++t2) {
      int oc = w * 32 + t2 * 16 + (l & 15);
      float* op = out + ((size_t)b * C2_ + oc) * HW_ + h * 64 + m * 16 + px0;
      *reinterpret_cast<f32x4*>(op) = acc[m][t2];
    }
}

// ---------------------------------------------------------------------------
extern "C" void kernel_launch(void* const* d_in, const int* in_sizes, int n_in,
                              void* d_out, int out_size, void* d_ws, size_t ws_size,
                              hipStream_t stream) {
  const float* x      = (const float*)d_in[0];
  const float* w_conv = (const float*)d_in[1];
  const float* w_off  = (const float*)d_in[2];
  const float* b_off  = (const float*)d_in[3];
  const float* w_mask = (const float*)d_in[4];
  const float* b_mask = (const float*)d_in[5];
  float* out = (float*)d_out;

  // workspace: om [16*27*4096] f32, then wpk [147456] bf16
  float* om = (float*)d_ws;
  unsigned short* wpk = (unsigned short*)(om + (size_t)B_ * NCH_ * HW_);

  hipLaunchKernelGGL(wpack_k, dim3((147456 + 255) / 256), dim3(256), 0, stream,
                     w_conv, wpk);
  hipLaunchKernelGGL(offmask_k, dim3(B_ * H_), dim3(256), 0, stream,
                     x, w_off, b_off, w_mask, b_mask, om);
  hipLaunchKernelGGL(dcn_k, dim3(B_ * H_), dim3(256), 0, stream,
                     x, wpk, om, out);
}

// Round 4
// 135.354 us; speedup vs baseline: 4.1383x; 2.8077x over previous
//
#include <hip/hip_runtime.h>
#include <math.h>

#define B_   16
#define C1_  128
#define C2_  128
#define H_   64
#define W_   64
#define HW_  4096
#define NCH_ 27

typedef __attribute__((ext_vector_type(8))) short  bf16x8;
typedef __attribute__((ext_vector_type(8))) unsigned short u16x8;
typedef __attribute__((ext_vector_type(4))) float  f32x4;

__device__ __forceinline__ unsigned short f2bf(float f) {
  unsigned int u = __builtin_bit_cast(unsigned int, f);
  u += 0x7fff + ((u >> 16) & 1);
  return (unsigned short)(u >> 16);
}
__device__ __forceinline__ float bf2f(unsigned short s) {
  return __builtin_bit_cast(float, ((unsigned int)s) << 16);
}

// ---------------------------------------------------------------------------
// Kernel A: x[b][c][h][w] f32 -> xcl[b][h][w][c] bf16 (channels-last).
// ---------------------------------------------------------------------------
__global__ __launch_bounds__(256) void xpose_k(const float* __restrict__ x,
                                               unsigned short* __restrict__ xcl) {
  __shared__ unsigned short tile[128][66];
  int bid = blockIdx.x;
  int bh = ((bid & 7) << 7) | (bid >> 3);
  int b = bh >> 6, h = bh & 63;
  int t = threadIdx.x;
  int wv = t & 63, cq = t >> 6;
  const float* xb = x + ((size_t)b * 128) * HW_ + h * 64;
#pragma unroll
  for (int i = 0; i < 32; ++i) {
    int c = i * 4 + cq;
    tile[c][wv] = f2bf(xb[(size_t)c * HW_ + wv]);
  }
  __syncthreads();
  int w2 = t >> 2, cg = (t & 3) * 32;
  unsigned short* op = xcl + (((size_t)bh) * 64 + w2) * 128 + cg;
#pragma unroll
  for (int i = 0; i < 4; ++i) {
    u16x8 pk;
#pragma unroll
    for (int j = 0; j < 8; ++j) pk[j] = tile[cg + i * 8 + j][w2];
    *reinterpret_cast<u16x8*>(op + i * 8) = pk;
  }
}

// ---------------------------------------------------------------------------
// Kernel B: pack w_conv into bf16 B-fragments (verified round 2).
// ---------------------------------------------------------------------------
__global__ __launch_bounds__(256) void wpack_k(const float* __restrict__ wc,
                                               unsigned short* __restrict__ wpk) {
  int idx = blockIdx.x * 256 + threadIdx.x;
  if (idx >= 9 * 8 * 4 * 64 * 8) return;
  int j  = idx & 7;
  int l  = (idx >> 3) & 63;
  int kb = (idx >> 9) & 3;
  int ot = (idx >> 11) & 7;
  int n  = idx >> 14;
  int oc = ot * 16 + (l & 15);
  int c  = kb * 32 + (l >> 4) * 8 + j;
  wpk[idx] = f2bf(wc[(oc * 128 + c) * 9 + n]);
}

// ---------------------------------------------------------------------------
// Kernel C: pack w_off/w_mask into B-frags.
// ---------------------------------------------------------------------------
__global__ __launch_bounds__(256) void wobpack_k(const float* __restrict__ w_off,
                                                 const float* __restrict__ w_mask,
                                                 unsigned short* __restrict__ wob) {
  int idx = blockIdx.x * 256 + threadIdx.x;
  if (idx >= 2 * 36 * 64 * 8) return;
  int j = idx & 7;
  int l = (idx >> 3) & 63;
  int rest = idx >> 9;
  int s = rest % 36;
  int nt = rest / 36;
  int ch = nt * 16 + (l & 15);
  int n = s >> 2;
  int c = (s & 3) * 32 + (l >> 4) * 8 + j;
  float v = 0.f;
  if (ch < 18) v = w_off[((ch * 128) + c) * 9 + n];
  else if (ch < 27) v = w_mask[(((ch - 18) * 128) + c) * 9 + n];
  wob[idx] = f2bf(v);
}

// ---------------------------------------------------------------------------
// Kernel D: offset+mask conv as MFMA GEMM. Block = (b,h) row.
// LDS: xr[3 rows][66 slots][128 c] bf16, XOR-swizzled (full-offset-then-XOR
// on BOTH write and read — round-3 bug was xor-before-add carry into bit 7).
// ---------------------------------------------------------------------------
__global__ __launch_bounds__(256) void offmask_k(
    const unsigned short* __restrict__ xcl,
    const unsigned short* __restrict__ wob,
    const float* __restrict__ b_off, const float* __restrict__ b_mask,
    float* __restrict__ om) {
  __shared__ char xr[3 * 66 * 256];   // 50688 B
  int bid = blockIdx.x;
  int bh = ((bid & 7) << 7) | (bid >> 3);
  int b = bh >> 6, h = bh & 63;
  int t = threadIdx.x;
  int l = t & 63, w = t >> 6;

  // stage rows h-1,h,h+1 with halo
#pragma unroll
  for (int ky = 0; ky < 3; ++ky) {
    int hh = h - 1 + ky;
    bool valid = (unsigned)hh < 64u;
    const unsigned short* src = xcl + (((size_t)b * 64 + (valid ? hh : 0)) * 64) * 128;
#pragma unroll
    for (int i = 0; i < 4; ++i) {
      int m = t + i * 256;
      int px = m >> 4;
      int c2 = (m & 15) * 16;
      unsigned off = (unsigned)((ky * 66 + px + 1) * 256 + c2) ^ (((px + 1) & 7) << 4);
      u16x8 v = {0, 0, 0, 0, 0, 0, 0, 0};
      if (valid) v = *reinterpret_cast<const u16x8*>(src + (size_t)m * 8);
      *reinterpret_cast<u16x8*>(xr + off) = v;
    }
  }
  if (t < 96) {   // halo slots 0 and 65 of each row
    int r = t >> 5, rem = t & 31;
    int slot = (rem < 16) ? 0 : 65;
    int c2 = (rem & 15) * 16;
    unsigned off = (unsigned)((r * 66 + slot) * 256 + c2) ^ ((slot & 7) << 4);
    u16x8 z = {0, 0, 0, 0, 0, 0, 0, 0};
    *reinterpret_cast<u16x8*>(xr + off) = z;
  }
  __syncthreads();

  f32x4 acc0 = (f32x4)0.f, acc1 = (f32x4)0.f;
#pragma unroll
  for (int n = 0; n < 9; ++n) {
    int ky = n / 3, kx = n % 3;
    int slot = w * 16 + (l & 15) + kx;
#pragma unroll
    for (int cs = 0; cs < 4; ++cs) {
      int s = n * 4 + cs;
      // FIX: full offset (incl. cs*64) computed BEFORE the XOR swizzle.
      unsigned aoff = (unsigned)((ky * 66 + slot) * 256 + (l >> 4) * 16 + cs * 64)
                      ^ ((unsigned)(slot & 7) << 4);
      bf16x8 afr = *reinterpret_cast<const bf16x8*>(xr + aoff);
      bf16x8 bf0 = *reinterpret_cast<const bf16x8*>(wob + ((size_t)(0 * 36 + s) * 64 + l) * 8);
      bf16x8 bf1 = *reinterpret_cast<const bf16x8*>(wob + ((size_t)(1 * 36 + s) * 64 + l) * 8);
      acc0 = __builtin_amdgcn_mfma_f32_16x16x32_bf16(afr, bf0, acc0, 0, 0, 0);
      acc1 = __builtin_amdgcn_mfma_f32_16x16x32_bf16(afr, bf1, acc1, 0, 0, 0);
    }
  }

  int pxo = w * 16 + (l >> 4) * 4;
#pragma unroll
  for (int nt = 0; nt < 2; ++nt) {
    int ch = nt * 16 + (l & 15);
    f32x4 v = (nt == 0) ? acc0 : acc1;
    if (ch < 27) {
      float bias = (ch < 18) ? b_off[ch] : b_mask[ch - 18];
#pragma unroll
      for (int r = 0; r < 4; ++r) {
        float y = v[r] + bias;
        if (ch >= 18) y = 1.f / (1.f + __expf(-y));
        v[r] = y;
      }
      *reinterpret_cast<f32x4*>(om + ((size_t)b * NCH_ + ch) * HW_ + h * 64 + pxo) = v;
    }
  }
}

// ---------------------------------------------------------------------------
// Kernel E: deformable sampling (dwordx4 from channels-last bf16) + MFMA GEMM.
// ---------------------------------------------------------------------------
__device__ __forceinline__ void dcn_issue(
    const unsigned short* __restrict__ xb, const float* __restrict__ omp_,
    int h, int spx, int c0, int n, float wt[4], u16x8 cv[4][4]) {
  float oy = omp_[(2 * n) * HW_ + spx];
  float ox = omp_[(2 * n + 1) * HW_ + spx];
  float m_ = omp_[(18 + n) * HW_ + spx];
  float py  = oy + (float)(h - 1 + n / 3);
  float pxf = ox + (float)(spx - 1 + n % 3);
  float y0f = floorf(py), x0f = floorf(pxf);
  int y0 = (int)y0f, x0 = (int)x0f;
  float wy1 = py - y0f, wx1 = pxf - x0f;
  float wy0 = 1.f - wy1, wx0 = 1.f - wx1;
  bool vy0 = (unsigned)y0 < 64u, vy1 = (unsigned)(y0 + 1) < 64u;
  bool vx0 = (unsigned)x0 < 64u, vx1 = (unsigned)(x0 + 1) < 64u;
  int y0c = min(max(y0, 0), 63), y1c = min(max(y0 + 1, 0), 63);
  int x0c = min(max(x0, 0), 63), x1c = min(max(x0 + 1, 0), 63);
  wt[0] = (vy0 && vx0) ? wy0 * wx0 * m_ : 0.f;
  wt[1] = (vy0 && vx1) ? wy0 * wx1 * m_ : 0.f;
  wt[2] = (vy1 && vx0) ? wy1 * wx0 * m_ : 0.f;
  wt[3] = (vy1 && vx1) ? wy1 * wx1 * m_ : 0.f;
  size_t i00 = ((size_t)(y0c * 64 + x0c)) * 128 + c0;
  size_t i01 = ((size_t)(y0c * 64 + x1c)) * 128 + c0;
  size_t i10 = ((size_t)(y1c * 64 + x0c)) * 128 + c0;
  size_t i11 = ((size_t)(y1c * 64 + x1c)) * 128 + c0;
#pragma unroll
  for (int cb = 0; cb < 4; ++cb) {
    cv[0][cb] = *reinterpret_cast<const u16x8*>(xb + i00 + cb * 8);
    cv[1][cb] = *reinterpret_cast<const u16x8*>(xb + i01 + cb * 8);
    cv[2][cb] = *reinterpret_cast<const u16x8*>(xb + i10 + cb * 8);
    cv[3][cb] = *reinterpret_cast<const u16x8*>(xb + i11 + cb * 8);
  }
}

__device__ __forceinline__ void dcn_commit(
    unsigned short* sbuf, int spx, int c0, const float wt[4], u16x8 cv[4][4]) {
#pragma unroll
  for (int cb = 0; cb < 4; ++cb) {
    u16x8 pk;
#pragma unroll
    for (int j = 0; j < 8; ++j) {
      float v = wt[0] * bf2f(cv[0][cb][j]) + wt[1] * bf2f(cv[1][cb][j])
              + wt[2] * bf2f(cv[2][cb][j]) + wt[3] * bf2f(cv[3][cb][j]);
      pk[j] = f2bf(v);
    }
    unsigned off = (unsigned)(spx * 256 + (c0 + cb * 8) * 2) ^ ((spx & 7) << 4);
    *reinterpret_cast<u16x8*>(reinterpret_cast<char*>(sbuf) + off) = pk;
  }
}

__global__ __launch_bounds__(256) void dcn_k(const unsigned short* __restrict__ xcl,
                                             const unsigned short* __restrict__ wpk,
                                             const float* __restrict__ om,
                                             float* __restrict__ out) {
  __shared__ unsigned short samp[2][64 * 128];   // 2 x 16 KB, swizzled

  int bid = blockIdx.x;
  int bh = ((bid & 7) << 7) | (bid >> 3);
  int b = bh >> 6, h = bh & 63;
  int t = threadIdx.x;
  int l = t & 63;
  int w = t >> 6;
  int spx = t & 63;
  int c0  = (t >> 6) * 32;

  f32x4 acc[4][2];
#pragma unroll
  for (int m = 0; m < 4; ++m)
#pragma unroll
    for (int t2 = 0; t2 < 2; ++t2) acc[m][t2] = (f32x4)0.f;

  const unsigned short* xb = xcl + ((size_t)b * HW_) * 128;
  const float* omp_ = om + (size_t)b * NCH_ * HW_ + h * 64;

  float wt[4];
  u16x8 cv[4][4];
  dcn_issue(xb, omp_, h, spx, c0, 0, wt, cv);
  dcn_commit(samp[0], spx, c0, wt, cv);
  __syncthreads();

  for (int n = 0; n < 9; ++n) {
    int cur = n & 1;
    if (n < 8) {
      dcn_issue(xb, omp_, h, spx, c0, n + 1, wt, cv);
      dcn_commit(samp[cur ^ 1], spx, c0, wt, cv);
    }

    const unsigned short* wp = wpk + (((size_t)n * 8 + w * 2) * 4) * 64 * 8;
    const char* sp = reinterpret_cast<const char*>(samp[cur]);
#pragma unroll
    for (int kb = 0; kb < 4; ++kb) {
      bf16x8 bfr0 = *reinterpret_cast<const bf16x8*>(wp + ((size_t)(0 * 4 + kb) * 64 + l) * 8);
      bf16x8 bfr1 = *reinterpret_cast<const bf16x8*>(wp + ((size_t)(1 * 4 + kb) * 64 + l) * 8);
      int kbyte = kb * 64 + (l >> 4) * 16;
#pragma unroll
      for (int m = 0; m < 4; ++m) {
        int px = m * 16 + (l & 15);
        unsigned off = (unsigned)(px * 256 + kbyte) ^ ((px & 7) << 4);
        bf16x8 afr = *reinterpret_cast<const bf16x8*>(sp + off);
        acc[m][0] = __builtin_amdgcn_mfma_f32_16x16x32_bf16(afr, bfr0, acc[m][0], 0, 0, 0);
        acc[m][1] = __builtin_amdgcn_mfma_f32_16x16x32_bf16(afr, bfr1, acc[m][1], 0, 0, 0);
      }
    }
    __syncthreads();
  }

  int px0 = (l >> 4) * 4;
#pragma unroll
  for (int m = 0; m < 4; ++m)
#pragma unroll
    for (int t2 = 0; t2 < 2; ++t2) {
      int oc = w * 32 + t2 * 16 + (l & 15);
      float* op = out + ((size_t)b * C2_ + oc) * HW_ + h * 64 + m * 16 + px0;
      *reinterpret_cast<f32x4*>(op) = acc[m][t2];
    }
}

// ---------------------------------------------------------------------------
extern "C" void kernel_launch(void* const* d_in, const int* in_sizes, int n_in,
                              void* d_out, int out_size, void* d_ws, size_t ws_size,
                              hipStream_t stream) {
  const float* x      = (const float*)d_in[0];
  const float* w_conv = (const float*)d_in[1];
  const float* w_off  = (const float*)d_in[2];
  const float* b_off  = (const float*)d_in[3];
  const float* w_mask = (const float*)d_in[4];
  const float* b_mask = (const float*)d_in[5];
  float* out = (float*)d_out;

  // ws layout: om f32 [16*27*4096] | wpk u16 [147456] | wob u16 [36864] | xcl u16 [16*4096*128]
  float* om = (float*)d_ws;
  unsigned short* wpk = (unsigned short*)(om + (size_t)B_ * NCH_ * HW_);
  unsigned short* wob = wpk + 147456;
  unsigned short* xcl = wob + 36864;

  hipLaunchKernelGGL(xpose_k, dim3(B_ * H_), dim3(256), 0, stream, x, xcl);
  hipLaunchKernelGGL(wpack_k, dim3(576), dim3(256), 0, stream, w_conv, wpk);
  hipLaunchKernelGGL(wobpack_k, dim3(144), dim3(256), 0, stream, w_off, w_mask, wob);
  hipLaunchKernelGGL(offmask_k, dim3(B_ * H_), dim3(256), 0, stream,
                     xcl, wob, b_off, b_mask, om);
  hipLaunchKernelGGL(dcn_k, dim3(B_ * H_), dim3(256), 0, stream,
                     xcl, wpk, om, out);
}

// Round 6
// 113.504 us; speedup vs baseline: 4.9349x; 1.1925x over previous
//
#include <hip/hip_runtime.h>
#include <math.h>

#define B_   16
#define C1_  128
#define C2_  128
#define H_   64
#define W_   64
#define HW_  4096
#define NCH_ 27

typedef __attribute__((ext_vector_type(8))) short  bf16x8;
typedef __attribute__((ext_vector_type(8))) unsigned short u16x8;
typedef __attribute__((ext_vector_type(4))) float  f32x4;
typedef __attribute__((ext_vector_type(4))) int    i32x4;
typedef __attribute__((ext_vector_type(4))) unsigned int u32x4;

__device__ __forceinline__ unsigned short f2bf(float f) {
  unsigned int u = __builtin_bit_cast(unsigned int, f);
  u += 0x7fff + ((u >> 16) & 1);
  return (unsigned short)(u >> 16);
}
__device__ __forceinline__ float lo16(unsigned int u) {
  return __builtin_bit_cast(float, u << 16);
}
__device__ __forceinline__ float hi16(unsigned int u) {
  return __builtin_bit_cast(float, u & 0xffff0000u);
}

// ---------------------------------------------------------------------------
// Kernel A: x[b][c][h][w] f32 -> xcl[b][h][w][c] bf16 (verified round 4).
// ---------------------------------------------------------------------------
__global__ __launch_bounds__(256) void xpose_k(const float* __restrict__ x,
                                               unsigned short* __restrict__ xcl) {
  __shared__ unsigned short tile[128][66];
  int bid = blockIdx.x;
  int bh = ((bid & 7) << 7) | (bid >> 3);
  int b = bh >> 6, h = bh & 63;
  int t = threadIdx.x;
  int wv = t & 63, cq = t >> 6;
  const float* xb = x + ((size_t)b * 128) * HW_ + h * 64;
#pragma unroll
  for (int i = 0; i < 32; ++i) {
    int c = i * 4 + cq;
    tile[c][wv] = f2bf(xb[(size_t)c * HW_ + wv]);
  }
  __syncthreads();
  int w2 = t >> 2, cg = (t & 3) * 32;
  unsigned short* op = xcl + (((size_t)bh) * 64 + w2) * 128 + cg;
#pragma unroll
  for (int i = 0; i < 4; ++i) {
    u16x8 pk;
#pragma unroll
    for (int j = 0; j < 8; ++j) pk[j] = tile[cg + i * 8 + j][w2];
    *reinterpret_cast<u16x8*>(op + i * 8) = pk;
  }
}

// ---------------------------------------------------------------------------
// Kernel B: pack w_conv into bf16 B-fragments (verified round 2).
// ---------------------------------------------------------------------------
__global__ __launch_bounds__(256) void wpack_k(const float* __restrict__ wc,
                                               unsigned short* __restrict__ wpk) {
  int idx = blockIdx.x * 256 + threadIdx.x;
  if (idx >= 9 * 8 * 4 * 64 * 8) return;
  int j  = idx & 7;
  int l  = (idx >> 3) & 63;
  int kb = (idx >> 9) & 3;
  int ot = (idx >> 11) & 7;
  int n  = idx >> 14;
  int oc = ot * 16 + (l & 15);
  int c  = kb * 32 + (l >> 4) * 8 + j;
  wpk[idx] = f2bf(wc[(oc * 128 + c) * 9 + n]);
}

// ---------------------------------------------------------------------------
// Kernel C: pack w_off/w_mask into B-frags (verified round 4).
// ---------------------------------------------------------------------------
__global__ __launch_bounds__(256) void wobpack_k(const float* __restrict__ w_off,
                                                 const float* __restrict__ w_mask,
                                                 unsigned short* __restrict__ wob) {
  int idx = blockIdx.x * 256 + threadIdx.x;
  if (idx >= 2 * 36 * 64 * 8) return;
  int j = idx & 7;
  int l = (idx >> 3) & 63;
  int rest = idx >> 9;
  int s = rest % 36;
  int nt = rest / 36;
  int ch = nt * 16 + (l & 15);
  int n = s >> 2;
  int c = (s & 3) * 32 + (l >> 4) * 8 + j;
  float v = 0.f;
  if (ch < 18) v = w_off[((ch * 128) + c) * 9 + n];
  else if (ch < 27) v = w_mask[(((ch - 18) * 128) + c) * 9 + n];
  wob[idx] = f2bf(v);
}

// ---------------------------------------------------------------------------
// Kernel D: offset+mask conv as MFMA GEMM (verified round 4, unchanged).
// ---------------------------------------------------------------------------
__global__ __launch_bounds__(256) void offmask_k(
    const unsigned short* __restrict__ xcl,
    const unsigned short* __restrict__ wob,
    const float* __restrict__ b_off, const float* __restrict__ b_mask,
    float* __restrict__ om) {
  __shared__ __attribute__((aligned(16))) char xr[3 * 66 * 256];
  int bid = blockIdx.x;
  int bh = ((bid & 7) << 7) | (bid >> 3);
  int b = bh >> 6, h = bh & 63;
  int t = threadIdx.x;
  int l = t & 63, w = t >> 6;

#pragma unroll
  for (int ky = 0; ky < 3; ++ky) {
    int hh = h - 1 + ky;
    bool valid = (unsigned)hh < 64u;
    const unsigned short* src = xcl + (((size_t)b * 64 + (valid ? hh : 0)) * 64) * 128;
#pragma unroll
    for (int i = 0; i < 4; ++i) {
      int m = t + i * 256;
      int px = m >> 4;
      int c2 = (m & 15) * 16;
      unsigned off = (unsigned)((ky * 66 + px + 1) * 256 + c2) ^ (((px + 1) & 7) << 4);
      u16x8 v = {0, 0, 0, 0, 0, 0, 0, 0};
      if (valid) v = *reinterpret_cast<const u16x8*>(src + (size_t)m * 8);
      *reinterpret_cast<u16x8*>(xr + off) = v;
    }
  }
  if (t < 96) {
    int r = t >> 5, rem = t & 31;
    int slot = (rem < 16) ? 0 : 65;
    int c2 = (rem & 15) * 16;
    unsigned off = (unsigned)((r * 66 + slot) * 256 + c2) ^ ((slot & 7) << 4);
    u16x8 z = {0, 0, 0, 0, 0, 0, 0, 0};
    *reinterpret_cast<u16x8*>(xr + off) = z;
  }
  __syncthreads();

  f32x4 acc0 = (f32x4)0.f, acc1 = (f32x4)0.f;
#pragma unroll
  for (int n = 0; n < 9; ++n) {
    int ky = n / 3, kx = n % 3;
    int slot = w * 16 + (l & 15) + kx;
#pragma unroll
    for (int cs = 0; cs < 4; ++cs) {
      int s = n * 4 + cs;
      unsigned aoff = (unsigned)((ky * 66 + slot) * 256 + (l >> 4) * 16 + cs * 64)
                      ^ ((unsigned)(slot & 7) << 4);
      bf16x8 afr = *reinterpret_cast<const bf16x8*>(xr + aoff);
      bf16x8 bf0 = *reinterpret_cast<const bf16x8*>(wob + ((size_t)(0 * 36 + s) * 64 + l) * 8);
      bf16x8 bf1 = *reinterpret_cast<const bf16x8*>(wob + ((size_t)(1 * 36 + s) * 64 + l) * 8);
      acc0 = __builtin_amdgcn_mfma_f32_16x16x32_bf16(afr, bf0, acc0, 0, 0, 0);
      acc1 = __builtin_amdgcn_mfma_f32_16x16x32_bf16(afr, bf1, acc1, 0, 0, 0);
    }
  }

  int pxo = w * 16 + (l >> 4) * 4;
#pragma unroll
  for (int nt = 0; nt < 2; ++nt) {
    int ch = nt * 16 + (l & 15);
    f32x4 v = (nt == 0) ? acc0 : acc1;
    if (ch < 27) {
      float bias = (ch < 18) ? b_off[ch] : b_mask[ch - 18];
#pragma unroll
      for (int r = 0; r < 4; ++r) {
        float y = v[r] + bias;
        if (ch >= 18) y = 1.f / (1.f + __expf(-y));
        v[r] = y;
      }
      *reinterpret_cast<f32x4*>(om + ((size_t)b * NCH_ + ch) * HW_ + h * 64 + pxo) = v;
    }
  }
}

// ---------------------------------------------------------------------------
// Kernel E v3b: barrier-free K-split deformable MFMA.
// Round-6 fixes vs v3: (1) aligned(16) LDS, (2) NO union — table and reduce
// buffers separate, (3) f2bf pair packing instead of inline-asm cvt_pk.
// ---------------------------------------------------------------------------
__device__ __forceinline__ bf16x8 blend4(u16x8 a, u16x8 b, u16x8 c, u16x8 d,
                                         float w0, float w1, float w2, float w3) {
  u32x4 ua = __builtin_bit_cast(u32x4, a);
  u32x4 ub = __builtin_bit_cast(u32x4, b);
  u32x4 uc = __builtin_bit_cast(u32x4, c);
  u32x4 ud = __builtin_bit_cast(u32x4, d);
  u32x4 r;
#pragma unroll
  for (int e = 0; e < 4; ++e) {
    float lo = w0 * lo16(ua[e]) + w1 * lo16(ub[e]) + w2 * lo16(uc[e]) + w3 * lo16(ud[e]);
    float hi = w0 * hi16(ua[e]) + w1 * hi16(ub[e]) + w2 * hi16(uc[e]) + w3 * hi16(ud[e]);
    r[e] = (unsigned)f2bf(lo) | ((unsigned)f2bf(hi) << 16);
  }
  return __builtin_bit_cast(bf16x8, r);
}

__global__ __launch_bounds__(256, 2) void dcn_k(
    const unsigned short* __restrict__ xcl,
    const unsigned short* __restrict__ wpk,
    const float* __restrict__ om,
    float* __restrict__ out) {
  __shared__ __attribute__((aligned(16))) float wtab[9 * 64 * 4];   //  9216 B
  __shared__ __attribute__((aligned(16))) int   itab[9 * 64 * 4];   //  9216 B
  __shared__ __attribute__((aligned(16))) float red[4 * 8 * 64 * 4]; // 32768 B

  int bid = blockIdx.x;
  int bh = ((bid & 7) << 7) | (bid >> 3);
  int b = bh >> 6, h = bh & 63;
  int t = threadIdx.x;
  int l = t & 63;
  int w = t >> 6;

  const unsigned short* xb = xcl + ((size_t)b * HW_) * 128;
  const float* omb = om + (size_t)b * NCH_ * HW_ + h * 64;

  // ---- phase 0: coord/weight table (one barrier) ----
  for (int e = t; e < 576; e += 256) {
    int n = e >> 6, px = e & 63;
    float oy = omb[(2 * n) * HW_ + px];
    float ox = omb[(2 * n + 1) * HW_ + px];
    float m_ = omb[(18 + n) * HW_ + px];
    float py  = oy + (float)(h - 1 + n / 3);
    float pxf = ox + (float)(px - 1 + n % 3);
    float y0f = floorf(py), x0f = floorf(pxf);
    int y0 = (int)y0f, x0 = (int)x0f;
    float wy1 = py - y0f, wx1 = pxf - x0f;
    float wy0 = 1.f - wy1, wx0 = 1.f - wx1;
    bool vy0 = (unsigned)y0 < 64u, vy1 = (unsigned)(y0 + 1) < 64u;
    bool vx0 = (unsigned)x0 < 64u, vx1 = (unsigned)(x0 + 1) < 64u;
    int y0c = min(max(y0, 0), 63), y1c = min(max(y0 + 1, 0), 63);
    int x0c = min(max(x0, 0), 63), x1c = min(max(x0 + 1, 0), 63);
    f32x4 wt4;
    wt4[0] = (vy0 && vx0) ? wy0 * wx0 * m_ : 0.f;
    wt4[1] = (vy0 && vx1) ? wy0 * wx1 * m_ : 0.f;
    wt4[2] = (vy1 && vx0) ? wy1 * wx0 * m_ : 0.f;
    wt4[3] = (vy1 && vx1) ? wy1 * wx1 * m_ : 0.f;
    i32x4 id4;
    id4[0] = (y0c * 64 + x0c) * 256;   // byte offsets (256 B per pixel)
    id4[1] = (y0c * 64 + x1c) * 256;
    id4[2] = (y1c * 64 + x0c) * 256;
    id4[3] = (y1c * 64 + x1c) * 256;
    *reinterpret_cast<f32x4*>(&wtab[e * 4]) = wt4;
    *reinterpret_cast<i32x4*>(&itab[e * 4]) = id4;
  }
  __syncthreads();

  // ---- phase 1: barrier-free main loop ----
  f32x4 acc[4][8];
#pragma unroll
  for (int m = 0; m < 4; ++m)
#pragma unroll
    for (int t2 = 0; t2 < 8; ++t2) acc[m][t2] = (f32x4)0.f;

  const char* xbc = reinterpret_cast<const char*>(xb);
  int cbyte = w * 64 + (l >> 4) * 16;   // this lane's 8-channel byte offset

  for (int n = 0; n < 9; ++n) {
    bf16x8 bfr[8];
#pragma unroll
    for (int t2 = 0; t2 < 8; ++t2)
      bfr[t2] = *reinterpret_cast<const bf16x8*>(
          wpk + (((size_t)(n * 8 + t2) * 4 + w) * 64 + l) * 8);

#pragma unroll
    for (int m = 0; m < 4; ++m) {
      int px = m * 16 + (l & 15);
      int te = n * 64 + px;
      f32x4 wt4 = *reinterpret_cast<const f32x4*>(&wtab[te * 4]);
      i32x4 id4 = *reinterpret_cast<const i32x4*>(&itab[te * 4]);
      u16x8 cv0 = *reinterpret_cast<const u16x8*>(xbc + id4[0] + cbyte);
      u16x8 cv1 = *reinterpret_cast<const u16x8*>(xbc + id4[1] + cbyte);
      u16x8 cv2 = *reinterpret_cast<const u16x8*>(xbc + id4[2] + cbyte);
      u16x8 cv3 = *reinterpret_cast<const u16x8*>(xbc + id4[3] + cbyte);
      bf16x8 afr = blend4(cv0, cv1, cv2, cv3, wt4[0], wt4[1], wt4[2], wt4[3]);
#pragma unroll
      for (int t2 = 0; t2 < 8; ++t2)
        acc[m][t2] = __builtin_amdgcn_mfma_f32_16x16x32_bf16(afr, bfr[t2], acc[m][t2], 0, 0, 0);
    }
  }

  // ---- phase 2: cross-wave reduction + store ----
#pragma unroll
  for (int m = 0; m < 4; ++m) {
#pragma unroll
    for (int t2 = 0; t2 < 8; ++t2)
      *reinterpret_cast<f32x4*>(&red[((w * 8 + t2) * 64 + l) * 4]) = acc[m][t2];
    __syncthreads();
#pragma unroll
    for (int i = 0; i < 2; ++i) {
      int t2o = w * 2 + i;
      f32x4 s = *reinterpret_cast<const f32x4*>(&red[((0 * 8 + t2o) * 64 + l) * 4]);
#pragma unroll
      for (int w2 = 1; w2 < 4; ++w2) {
        f32x4 p = *reinterpret_cast<const f32x4*>(&red[((w2 * 8 + t2o) * 64 + l) * 4]);
        s[0] += p[0]; s[1] += p[1]; s[2] += p[2]; s[3] += p[3];
      }
      int oc = t2o * 16 + (l & 15);
      int px0 = m * 16 + (l >> 4) * 4;
      *reinterpret_cast<f32x4*>(out + ((size_t)b * C2_ + oc) * HW_ + h * 64 + px0) = s;
    }
    __syncthreads();   // protect red before next m overwrites
  }
}

// ---------------------------------------------------------------------------
extern "C" void kernel_launch(void* const* d_in, const int* in_sizes, int n_in,
                              void* d_out, int out_size, void* d_ws, size_t ws_size,
                              hipStream_t stream) {
  const float* x      = (const float*)d_in[0];
  const float* w_conv = (const float*)d_in[1];
  const float* w_off  = (const float*)d_in[2];
  const float* b_off  = (const float*)d_in[3];
  const float* w_mask = (const float*)d_in[4];
  const float* b_mask = (const float*)d_in[5];
  float* out = (float*)d_out;

  // ws layout: om f32 [16*27*4096] | wpk u16 [147456] | wob u16 [36864] | xcl u16 [16*4096*128]
  float* om = (float*)d_ws;
  unsigned short* wpk = (unsigned short*)(om + (size_t)B_ * NCH_ * HW_);
  unsigned short* wob = wpk + 147456;
  unsigned short* xcl = wob + 36864;

  hipLaunchKernelGGL(xpose_k, dim3(B_ * H_), dim3(256), 0, stream, x, xcl);
  hipLaunchKernelGGL(wpack_k, dim3(576), dim3(256), 0, stream, w_conv, wpk);
  hipLaunchKernelGGL(wobpack_k, dim3(144), dim3(256), 0, stream, w_off, w_mask, wob);
  hipLaunchKernelGGL(offmask_k, dim3(B_ * H_), dim3(256), 0, stream,
                     xcl, wob, b_off, b_mask, om);
  hipLaunchKernelGGL(dcn_k, dim3(B_ * H_), dim3(256), 0, stream,
                     xcl, wpk, om, out);
}